// Round 11
// baseline (446.490 us; speedup 1.0000x reference)
//
#include <hip/hip_runtime.h>
#include <hip/hip_bf16.h>

// B=8, S=1024, H=16, D=64, E=1024. I/O fp32; internal bf16 MFMA.
// attn = softmax over QUERY axis C (per key row c) of tril(K Q^T)/8.
// Two-pass: l_c = sum_{C<=c} exp(s_cC/8); then z[C] = sum_{c>=C}
// (exp(s_cC/8)/l_c) * v_c, with 1/l folded into P (vscale removed, R14).
// R19: attn_av split across 2 waves per block (R18 recipe; counters showed
// it grid-limited: 116 VGPR, 15% occupancy, 2048 waves = 2/SIMD supply).
// Wave 0 = keys [Cw, mid), wave 1 = [mid, SEQ), mid=(Cw+SEQ)/2 -> equal
// (16-j) 32-key steps/wave. Per-wave pipeline unchanged (own P ping-pong,
// no loop barriers); zacc combined via one LDS round-trip reusing P
// (20KB -> 8 blocks/CU); masks unified to dynamic kt-vs-qt rule (provably
// == R14's enumerated masks); odd step counts peeled R10-style.
// attn_stats: R18 2-wave split form. GEMMs/cvt: R14 forms.

#define SEQ 1024
#define DH 64
#define NH 16
#define EMB 1024
#define SCALE 0.18033688011112042f  // 0.125 * log2(e)
#define PSTR 40                     // P row stride (u16), 80B = 16B-aligned

#define ZEROM 0
#define DIAGM 1
#define FULLM 2

typedef float f32x4 __attribute__((ext_vector_type(4)));
typedef __bf16 bf16x8 __attribute__((ext_vector_type(8)));
typedef unsigned short u16x8 __attribute__((ext_vector_type(8)));

__device__ __forceinline__ unsigned short f2bf(float f) {
  union { float f; unsigned int u; } v; v.f = f;
  unsigned int u = v.u;
  return (unsigned short)((u + 0x7fffu + ((u >> 16) & 1u)) >> 16);  // RNE
}
__device__ __forceinline__ unsigned short f2bf_fast(float f) {
  union { float f; unsigned int u; } v; v.f = f;
  return (unsigned short)((v.u + 0x8000u) >> 16);  // round-half-up (p>=0)
}
__device__ __forceinline__ float bf2f(unsigned short u) {
  union { unsigned int u; float f; } v; v.u = ((unsigned int)u) << 16; return v.f;
}

__device__ __forceinline__ u16x8 ld8_f32_bf16(const float* g) {
  const float4 a = *(const float4*)g;
  const float4 b = *(const float4*)(g + 4);
  u16x8 r;
  r[0] = f2bf(a.x); r[1] = f2bf(a.y); r[2] = f2bf(a.z); r[3] = f2bf(a.w);
  r[4] = f2bf(b.x); r[5] = f2bf(b.y); r[6] = f2bf(b.z); r[7] = f2bf(b.w);
  return r;
}

__device__ __forceinline__ void gl_lds16(const void* g, void* l) {
  __builtin_amdgcn_global_load_lds(
      (const __attribute__((address_space(1))) void*)g,
      (__attribute__((address_space(3))) void*)l, 16, 0, 0);
}

// ---------------- fp32 -> bf16 conversion of X and weights ----------------
__global__ __launch_bounds__(256) void cvt_bf16(
    const float* __restrict__ X, const float* __restrict__ Wk,
    const float* __restrict__ Wq, const float* __restrict__ Wv,
    const float* __restrict__ Wo,
    unsigned short* __restrict__ Xb, unsigned short* __restrict__ Wkb,
    unsigned short* __restrict__ Wqb, unsigned short* __restrict__ Wvb,
    unsigned short* __restrict__ Wob)
{
  const size_t i = ((size_t)blockIdx.x * 256 + threadIdx.x) * 8;
  const float* src; unsigned short* dst; size_t off;
  if (i < 8388608) { src = X; dst = Xb; off = i; }
  else {
    const size_t j = i - 8388608;
    const int sel = (int)(j >> 20); off = j & 1048575;
    src = (sel == 0) ? Wk : (sel == 1) ? Wq : (sel == 2) ? Wv : Wo;
    dst = (sel == 0) ? Wkb : (sel == 1) ? Wqb : (sel == 2) ? Wvb : Wob;
  }
  *(u16x8*)(dst + off) = ld8_f32_bf16(src + off);
}

// ---------------- GEMM core (BK=64, xor-swizzled LDS) ----------------
#define GEMM_BK64_BODY(Aptr, Bptr)                                              \
  f32x4 acc[4][4] = {};                                                         \
  const int srow = lane >> 3;                                                   \
  const int scol = (((lane & 7) ^ srow)) * 8;                                   \
  const unsigned short* Ag = (Aptr) + (size_t)(mt0 + wave * 32 + srow) * EMB + scol; \
  const unsigned short* Bg = (Bptr) + (size_t)(n0 + wave * 32 + srow) * EMB + scol;  \
  char* lA = (char*)As + wave * 4096;                                           \
  char* lB = (char*)Bs + wave * 4096;                                           \
  for (int k0 = 0; k0 < EMB; k0 += 64) {                                        \
    __syncthreads();                                                            \
    _Pragma("unroll")                                                           \
    for (int ch = 0; ch < 4; ch++) {                                            \
      gl_lds16(Ag + (size_t)ch * 8 * EMB + k0, lA + ch * 1024);                 \
      gl_lds16(Bg + (size_t)ch * 8 * EMB + k0, lB + ch * 1024);                 \
    }                                                                           \
    __syncthreads();                                                            \
    _Pragma("unroll")                                                           \
    for (int half = 0; half < 2; half++) {                                      \
      bf16x8 af[4], bfr[4];                                                     \
      _Pragma("unroll")                                                         \
      for (int t = 0; t < 4; t++) {                                             \
        const int ra = wm * 64 + t * 16 + fr;                                   \
        const int rb = wn * 64 + t * 16 + fr;                                   \
        af[t]  = *(const bf16x8*)&As[ra * 64 + (((half * 4 + quad) ^ (ra & 7)) * 8)]; \
        bfr[t] = *(const bf16x8*)&Bs[rb * 64 + (((half * 4 + quad) ^ (rb & 7)) * 8)]; \
      }                                                                         \
      _Pragma("unroll")                                                         \
      for (int i = 0; i < 4; i++)                                               \
        _Pragma("unroll")                                                       \
        for (int j = 0; j < 4; j++)                                             \
          acc[i][j] = __builtin_amdgcn_mfma_f32_16x16x32_bf16(af[i], bfr[j], acc[i][j], 0, 0, 0); \
    }                                                                           \
  }

// ---------------- GEMM: QKV projection ----------------
__global__ __launch_bounds__(256) void gemm_qkv(
    const unsigned short* __restrict__ X,
    const unsigned short* __restrict__ Wk,
    const unsigned short* __restrict__ Wq,
    const unsigned short* __restrict__ Wv,
    unsigned short* __restrict__ Kb,
    unsigned short* __restrict__ Qb,
    unsigned short* __restrict__ Vt)
{
  __shared__ __align__(16) unsigned short As[128 * 64];
  __shared__ __align__(16) unsigned short Bs[128 * 64];
  const int mt0 = blockIdx.x * 128;
  const int nt = blockIdx.y;
  const int sel = nt >> 3;
  const int n0 = (nt & 7) * 128;
  const unsigned short* W = (sel == 0) ? Wk : (sel == 1) ? Wq : Wv;

  const int tid = threadIdx.x;
  const int wave = tid >> 6, lane = tid & 63;
  const int wm = wave >> 1, wn = wave & 1;
  const int fr = lane & 15, quad = lane >> 4;

  GEMM_BK64_BODY(X, W)

  const int rl = quad * 4;
  if (sel < 2) {
    unsigned short* Dst = (sel == 0) ? Kb : Qb;
#pragma unroll
    for (int i = 0; i < 4; i++) {
      const int col = n0 + wn * 64 + i * 16 + fr;
      const int a = col >> 6, h = col & 63;
#pragma unroll
      for (int j = 0; j < 4; j++) {
        const int rowb = mt0 + wm * 64 + j * 16 + rl;
#pragma unroll
        for (int r = 0; r < 4; r++) {
          const int row = rowb + r;
          const int b = row >> 10, s = row & 1023;
          Dst[(size_t)((b * NH + a) * SEQ + s) * DH + h] = f2bf(acc[j][i][r]);
        }
      }
    }
  } else {
#pragma unroll
    for (int i = 0; i < 4; i++) {
      const int col = n0 + wn * 64 + i * 16 + fr;
      const int a = col >> 6, h = col & 63;
#pragma unroll
      for (int j = 0; j < 4; j++) {
        const int rowb = mt0 + wm * 64 + j * 16 + rl;
#pragma unroll
        for (int r = 0; r < 4; r++) {
          const int row = rowb + r;
          const int b = row >> 10, s = row & 1023;
          Vt[(size_t)((b * NH + a) * DH + h) * SEQ + s] = f2bf(acc[j][i][r]);
        }
      }
    }
  }
}

// ---------------- GEMM: output projection (bf16 in, fp32 out) ----------------
__global__ __launch_bounds__(256) void gemm_out(
    const unsigned short* __restrict__ Z,
    const unsigned short* __restrict__ Wo,
    float* __restrict__ Out)
{
  __shared__ __align__(16) unsigned short As[128 * 64];
  __shared__ __align__(16) unsigned short Bs[128 * 64];
  const int mt0 = blockIdx.x * 128;
  const int n0 = blockIdx.y * 128;

  const int tid = threadIdx.x;
  const int wave = tid >> 6, lane = tid & 63;
  const int wm = wave >> 1, wn = wave & 1;
  const int fr = lane & 15, quad = lane >> 4;

  GEMM_BK64_BODY(Z, Wo)

  const int rl = quad * 4;
#pragma unroll
  for (int i = 0; i < 4; i++) {
    const int col = n0 + wn * 64 + i * 16 + fr;
#pragma unroll
    for (int j = 0; j < 4; j++) {
      const int rowb = mt0 + wm * 64 + j * 16 + rl;
#pragma unroll
      for (int r = 0; r < 4; r++)
        Out[(size_t)(rowb + r) * EMB + col] = acc[j][i][r];
    }
  }
}

// ---------------- stats tile: accumulate exp into l4 ----------------
__device__ __forceinline__ void st_tile(
    const bf16x8* ka, const bf16x8* q, float* l4, int mode, int fr, int quad)
{
  f32x4 a = {0.f, 0.f, 0.f, 0.f};
  a = __builtin_amdgcn_mfma_f32_16x16x32_bf16(ka[0], q[0], a, 0, 0, 0);
  a = __builtin_amdgcn_mfma_f32_16x16x32_bf16(ka[1], q[1], a, 0, 0, 0);
#pragma unroll
  for (int i = 0; i < 4; i++) {
    const float e = exp2f(a[i] * SCALE);
    l4[i] += (mode == FULLM || fr <= quad * 4 + i) ? e : 0.f;
  }
}

// ---------------- Pass 1: l_c = sum_{C<=c} exp(s_cC/8) ----------------
// 2-wave blocks (128 thr), query-range split (R18). grid (128, 16).
__global__ __launch_bounds__(128, 4) void attn_stats(
    const unsigned short* __restrict__ Kb, const unsigned short* __restrict__ Qb,
    float* __restrict__ Ls)
{
  __shared__ float lred[2][64];
  const int head = blockIdx.x;
  const int j = 15 - (int)blockIdx.y;
  const int cw = j * 64;
  const int tid = threadIdx.x;
  const int wave = tid >> 6;
  const int lane = tid & 63;
  const int fr = lane & 15, quad = lane >> 4;
  const unsigned short* Kl = Kb + (size_t)head * (SEQ * DH) + (size_t)fr * DH + quad * 8;
  const unsigned short* Ql = Qb + (size_t)head * (SEQ * DH) + (size_t)fr * DH + quad * 8;

  bf16x8 ka[4][2];
#pragma unroll
  for (int s = 0; s < 4; s++)
#pragma unroll
    for (int h = 0; h < 2; h++)
      ka[s][h] = *(const bf16x8*)(Kl + (size_t)(cw + s * 16) * DH + h * 32);

  float l[4][4] = {};

  // full region: 2j 32-query blocks, all FULLM. wave0 [0,j), wave1 [j,2j).
  const int qb0 = wave ? j : 0;
  const int qb1 = wave ? 2 * j : j;
  if (qb0 < qb1) {
    bf16x8 qc0[2], qc1[2];
    {
      const unsigned short* qp = Ql + (size_t)(qb0 * 32) * DH;
      qc0[0] = *(const bf16x8*)(qp);
      qc0[1] = *(const bf16x8*)(qp + 32);
      qc1[0] = *(const bf16x8*)(qp + (size_t)16 * DH);
      qc1[1] = *(const bf16x8*)(qp + (size_t)16 * DH + 32);
    }
    for (int qb = qb0; qb < qb1; qb++) {
      bf16x8 qn0[2] = {qc0[0], qc0[1]};
      bf16x8 qn1[2] = {qc1[0], qc1[1]};
      if (qb + 1 < qb1) {
        const unsigned short* qp = Ql + (size_t)((qb + 1) * 32) * DH;
        qn0[0] = *(const bf16x8*)(qp);
        qn0[1] = *(const bf16x8*)(qp + 32);
        qn1[0] = *(const bf16x8*)(qp + (size_t)16 * DH);
        qn1[1] = *(const bf16x8*)(qp + (size_t)16 * DH + 32);
      }
#pragma unroll
      for (int s = 0; s < 4; s++) {
        st_tile(ka[s], qc0, l[s], FULLM, fr, quad);
        st_tile(ka[s], qc1, l[s], FULLM, fr, quad);
      }
      qc0[0] = qn0[0]; qc0[1] = qn0[1];
      qc1[0] = qn1[0]; qc1[1] = qn1[1];
    }
  }

  if (wave == 1) {  // diagonal 64x64 block (round-0 peel, verbatim masks)
    {  // queries local [0,32)
      bf16x8 q0[2], q1[2];
#pragma unroll
      for (int h = 0; h < 2; h++) {
        q0[h] = *(const bf16x8*)(Ql + (size_t)cw * DH + h * 32);
        q1[h] = *(const bf16x8*)(Ql + (size_t)(cw + 16) * DH + h * 32);
      }
      st_tile(ka[0], q0, l[0], DIAGM, fr, quad);
      st_tile(ka[1], q0, l[1], FULLM, fr, quad);
      st_tile(ka[2], q0, l[2], FULLM, fr, quad);
      st_tile(ka[3], q0, l[3], FULLM, fr, quad);
      st_tile(ka[1], q1, l[1], DIAGM, fr, quad);
      st_tile(ka[2], q1, l[2], FULLM, fr, quad);
      st_tile(ka[3], q1, l[3], FULLM, fr, quad);
    }
    {  // queries local [32,64)
      bf16x8 q0[2], q1[2];
#pragma unroll
      for (int h = 0; h < 2; h++) {
        q0[h] = *(const bf16x8*)(Ql + (size_t)(cw + 32) * DH + h * 32);
        q1[h] = *(const bf16x8*)(Ql + (size_t)(cw + 48) * DH + h * 32);
      }
      st_tile(ka[2], q0, l[2], DIAGM, fr, quad);
      st_tile(ka[3], q0, l[3], FULLM, fr, quad);
      st_tile(ka[3], q1, l[3], DIAGM, fr, quad);
    }
  }

  // fr-shfl reduce within wave -> lred; cross-wave add; store.
#pragma unroll
  for (int s = 0; s < 4; s++)
#pragma unroll
    for (int i = 0; i < 4; i++) {
      float v = l[s][i];
      v += __shfl_xor(v, 1); v += __shfl_xor(v, 2);
      v += __shfl_xor(v, 4); v += __shfl_xor(v, 8);
      if (fr == 0) lred[wave][s * 16 + quad * 4 + i] = v;
    }
  __syncthreads();
  if (tid < 64)
    Ls[(size_t)head * SEQ + cw + tid] = lred[0][tid] + lred[1][tid];
}

// ------- load 2x float4 of l and reciprocate (keys kb..kb+31) -------
__device__ __forceinline__ void ldrl(const float* Lh, int kb, int quad,
                                     f32x4* r0, f32x4* r1)
{
  const float4 a = *(const float4*)(Lh + kb + quad * 4);
  const float4 b = *(const float4*)(Lh + kb + 16 + quad * 4);
  (*r0)[0] = __builtin_amdgcn_rcpf(a.x); (*r0)[1] = __builtin_amdgcn_rcpf(a.y);
  (*r0)[2] = __builtin_amdgcn_rcpf(a.z); (*r0)[3] = __builtin_amdgcn_rcpf(a.w);
  (*r1)[0] = __builtin_amdgcn_rcpf(b.x); (*r1)[1] = __builtin_amdgcn_rcpf(b.y);
  (*r1)[2] = __builtin_amdgcn_rcpf(b.z); (*r1)[3] = __builtin_amdgcn_rcpf(b.w);
}

// -------- av score tile -> LDS, scaled by rcp(l[key]) --------
__device__ __forceinline__ void av_tile_s(
    const bf16x8* ka, const bf16x8* bq, const f32x4 rl,
    unsigned short* __restrict__ pw, int mode, int fr, int quad)
{
  if (mode == ZEROM) { *(uint2*)pw = make_uint2(0u, 0u); return; }
  f32x4 acc = {0.f, 0.f, 0.f, 0.f};
  acc = __builtin_amdgcn_mfma_f32_16x16x32_bf16(ka[0], bq[0], acc, 0, 0, 0);
  acc = __builtin_amdgcn_mfma_f32_16x16x32_bf16(ka[1], bq[1], acc, 0, 0, 0);
  unsigned short us[4];
#pragma unroll
  for (int i = 0; i < 4; i++) {
    float p = exp2f(acc[i] * SCALE) * rl[i];   // row = key = quad*4+i
    if (mode == DIAGM && (quad * 4 + i < fr)) p = 0.f;
    us[i] = f2bf_fast(p);
  }
  uint2 pk;
  pk.x = (unsigned)us[0] | ((unsigned)us[1] << 16);
  pk.y = (unsigned)us[2] | ((unsigned)us[3] << 16);
  *(uint2*)pw = pk;
}

// score 32 keys at kt (two 16-key subtiles) for all 4 q-tiles -> Pdst.
// mode per tile from 16-aligned key/query tile compare (== R14 masks).
#define SCORE32(Pdst, kf0, kf1, kt)                                             \
  _Pragma("unroll")                                                             \
  for (int t = 0; t < 4; t++) {                                                 \
    unsigned short* pw = &(Pdst)[t * (16 * PSTR) + fr * PSTR + quad * 4];       \
    const int qt_ = Cw + t * 16;                                                \
    av_tile_s(kf0, bq[t], rl0, pw,                                              \
              ((kt) > qt_) ? FULLM : (((kt) == qt_) ? DIAGM : ZEROM), fr, quad);\
    av_tile_s(kf1, bq[t], rl1, pw + 16,                                         \
              ((kt) + 16 > qt_) ? FULLM : (((kt) + 16 == qt_) ? DIAGM : ZEROM), \
              fr, quad);                                                        \
  }

#define PF_READ(Psrc)                                                           \
  _Pragma("unroll")                                                             \
  for (int t = 0; t < 4; t++)                                                   \
    pf[t] = *(const bf16x8*)&(Psrc)[t * (16 * PSTR) + fr * PSTR + quad * 8];

#define PV_ACC(vv)                                                              \
  _Pragma("unroll")                                                             \
  for (int t = 0; t < 4; t++)                                                   \
    _Pragma("unroll")                                                           \
    for (int n = 0; n < 4; n++)                                                 \
      zacc[t][n] = __builtin_amdgcn_mfma_f32_16x16x32_bf16(pf[t], (vv)[n], zacc[t][n], 0, 0, 0);

// ---------------- Pass 2: z = sum_c (P_cC / l_c) v_c ----------------
// 2-wave blocks (128 thr): wave 0 keys [Cw, mid), wave 1 [mid, SEQ),
// mid=(Cw+SEQ)/2 -> equal (16-j) 32-key steps/wave. Per-wave R14 pipeline
// (own P ping-pong, no loop barriers, PV-first); odd steps peeled; zacc
// combined via LDS (reuses P). grid (128 heads, 16 chunks), j=0 heaviest.
__global__ __launch_bounds__(128, 3) void attn_av(
    const unsigned short* __restrict__ Kb, const unsigned short* __restrict__ Qb,
    const unsigned short* __restrict__ Vt, const float* __restrict__ Ls,
    unsigned short* __restrict__ Z)
{
  __shared__ __align__(16) unsigned short P[2][2][4 * 16 * PSTR];  // 20480 B
  const int head = blockIdx.x;
  const int j = blockIdx.y;
  const int Cw = j * 64;
  const int tid = threadIdx.x;
  const int w = tid >> 6;
  const int lane = tid & 63;
  const int fr = lane & 15, quad = lane >> 4;
  const int mid = 512 + 32 * j;             // (Cw + SEQ) / 2, 32-aligned
  const int ks = w ? mid : Cw;
  const int ke = w ? SEQ : mid;
  const unsigned short* Kl = Kb + (size_t)head * (SEQ * DH) + (size_t)fr * DH + quad * 8;
  const unsigned short* Ql = Qb + (size_t)head * (SEQ * DH) + (size_t)fr * DH + quad * 8;
  const unsigned short* Vl = Vt + (size_t)head * (SEQ * DH) + (size_t)fr * SEQ + quad * 8;
  const float* Lh = Ls + (size_t)head * SEQ;

  bf16x8 bq[4][2];
#pragma unroll
  for (int t = 0; t < 4; t++)
#pragma unroll
    for (int h = 0; h < 2; h++)
      bq[t][h] = *(const bf16x8*)(Ql + (size_t)(Cw + t * 16) * DH + h * 32);

  f32x4 zacc[4][4] = {};
  bf16x8 kA0[2], kA1[2], kB0[2], kB1[2], vA[4], vB[4];
  unsigned short* Pa = &P[w][0][0];
  unsigned short* Pb = &P[w][1][0];

  {  // prologue: scores for keys [ks, ks+32) -> Pa (dynamic masks)
    f32x4 rl0, rl1;
    ldrl(Lh, ks, quad, &rl0, &rl1);
    bf16x8 kp0[2], kp1[2];
#pragma unroll
    for (int h = 0; h < 2; h++) {
      kp0[h] = *(const bf16x8*)(Kl + (size_t)ks * DH + h * 32);
      kp1[h] = *(const bf16x8*)(Kl + (size_t)(ks + 16) * DH + h * 32);
    }
    SCORE32(Pa, kp0, kp1, ks)
  }
  if (ks + 32 < ke) {  // kA = keys [ks+32, ks+64)
#pragma unroll
    for (int h = 0; h < 2; h++) {
      kA0[h] = *(const bf16x8*)(Kl + (size_t)(ks + 32) * DH + h * 32);
      kA1[h] = *(const bf16x8*)(Kl + (size_t)(ks + 48) * DH + h * 32);
    }
  }
#pragma unroll
  for (int n = 0; n < 4; n++)  // vA = V(ks)
    vA[n] = *(const bf16x8*)(Vl + (size_t)(n * 16) * SEQ + ks);

  int kb = ks;
  const int steps = (ke - ks) >> 5;  // = 16 - j per wave
  if (steps & 1) {  // peel one 32-key step
    bf16x8 pf[4];
    PF_READ(Pa)
    const bool has2 = (kb + 32 < ke);
    f32x4 rl0, rl1;
    if (has2) {
      ldrl(Lh, kb + 32, quad, &rl0, &rl1);
      if (kb + 64 < ke) {
#pragma unroll
        for (int h = 0; h < 2; h++) {
          kB0[h] = *(const bf16x8*)(Kl + (size_t)(kb + 64) * DH + h * 32);
          kB1[h] = *(const bf16x8*)(Kl + (size_t)(kb + 80) * DH + h * 32);
        }
      }
#pragma unroll
      for (int n = 0; n < 4; n++)
        vB[n] = *(const bf16x8*)(Vl + (size_t)(n * 16) * SEQ + (kb + 32));
      SCORE32(Pb, kA0, kA1, kb + 32)
    }
    PV_ACC(vA)
    if (has2) {
      kA0[0] = kB0[0]; kA0[1] = kB0[1];
      kA1[0] = kB1[0]; kA1[1] = kB1[1];
#pragma unroll
      for (int n = 0; n < 4; n++) vA[n] = vB[n];
      unsigned short* tp = Pa; Pa = Pb; Pb = tp;
    }
    kb += 32;
  }

  for (; kb < ke; kb += 64) {  // even # of 32-key steps remain
    {  // half A: PV(kb) from Pa; scores keys [kb+32, kb+64) -> Pb
      bf16x8 pf[4];
      PF_READ(Pa)
      const int nxt = kb + 32;  // < ke (even count)
      f32x4 rl0, rl1;
      ldrl(Lh, nxt, quad, &rl0, &rl1);
      if (kb + 64 < ke) {
#pragma unroll
        for (int h = 0; h < 2; h++) {
          kB0[h] = *(const bf16x8*)(Kl + (size_t)(kb + 64) * DH + h * 32);
          kB1[h] = *(const bf16x8*)(Kl + (size_t)(kb + 80) * DH + h * 32);
        }
      }
#pragma unroll
      for (int n = 0; n < 4; n++)
        vB[n] = *(const bf16x8*)(Vl + (size_t)(n * 16) * SEQ + nxt);
      PV_ACC(vA)
      SCORE32(Pb, kA0, kA1, nxt)
    }
    {  // half B: PV(kb+32) from Pb; scores keys [kb+64, kb+96) -> Pa
      bf16x8 pf[4];
      PF_READ(Pb)
      const int nxt2 = kb + 64;
      f32x4 rl0, rl1;
      if (nxt2 < ke) {
        ldrl(Lh, nxt2, quad, &rl0, &rl1);
        if (kb + 96 < ke) {
#pragma unroll
          for (int h = 0; h < 2; h++) {
            kA0[h] = *(const bf16x8*)(Kl + (size_t)(kb + 96) * DH + h * 32);
            kA1[h] = *(const bf16x8*)(Kl + (size_t)(kb + 112) * DH + h * 32);
          }
        }
#pragma unroll
        for (int n = 0; n < 4; n++)
          vA[n] = *(const bf16x8*)(Vl + (size_t)(n * 16) * SEQ + nxt2);
        PV_ACC(vB)
        SCORE32(Pa, kB0, kB1, nxt2)
      } else {
        PV_ACC(vB)
      }
    }
  }

  // cross-wave zacc combine (reuse P as float scratch: 16 KB < 20480 B)
  __syncthreads();
  float* zred = (float*)&P[0][0][0];
  if (w == 1) {
#pragma unroll
    for (int t = 0; t < 4; t++)
#pragma unroll
      for (int n = 0; n < 4; n++)
#pragma unroll
        for (int i = 0; i < 4; i++)
          zred[(((t * 4 + n) * 4 + i) << 6) + lane] = zacc[t][n][i];
  }
  __syncthreads();
  if (w == 0) {
    const int b = head >> 4, a = head & 15;
#pragma unroll
    for (int t = 0; t < 4; t++)
#pragma unroll
      for (int n = 0; n < 4; n++)
#pragma unroll
        for (int i = 0; i < 4; i++) {
          const float zv = zacc[t][n][i] + zred[(((t * 4 + n) * 4 + i) << 6) + lane];
          const int C = Cw + t * 16 + quad * 4 + i;
          const int f = a * DH + n * 16 + fr;
          Z[((size_t)(b * SEQ + C) << 10) + f] = f2bf(zv);
        }
  }
}

// ---------------- launch ----------------
extern "C" void kernel_launch(void* const* d_in, const int* in_sizes, int n_in,
                              void* d_out, int out_size, void* d_ws, size_t ws_size,
                              hipStream_t stream)
{
  const float* x  = (const float*)d_in[0];
  const float* wk = (const float*)d_in[1];
  const float* wq = (const float*)d_in[2];
  const float* wv = (const float*)d_in[3];
  const float* wo = (const float*)d_in[4];
  float* out = (float*)d_out;
  char* ws = (char*)d_ws;

  unsigned short* Xb  = (unsigned short*)(ws);            // 16 MB (aliased by Zb)
  unsigned short* Zb  = (unsigned short*)(ws);
  unsigned short* Kb  = (unsigned short*)(ws + 16777216);
  unsigned short* Qb  = (unsigned short*)(ws + 33554432);
  unsigned short* Vtb = (unsigned short*)(ws + 50331648);
  unsigned short* Wkb = (unsigned short*)(ws + 67108864);
  unsigned short* Wqb = (unsigned short*)(ws + 69206016);
  unsigned short* Wvb = (unsigned short*)(ws + 71303168);
  unsigned short* Wob = (unsigned short*)(ws + 73400320);
  float* Ls = (float*)(ws + 75497472);

  cvt_bf16<<<dim3(6144), 256, 0, stream>>>(x, wk, wq, wv, wo, Xb, Wkb, Wqb, Wvb, Wob);
  gemm_qkv<<<dim3(64, 24), 256, 0, stream>>>(Xb, Wkb, Wqb, Wvb, Kb, Qb, Vtb);
  attn_stats<<<dim3(128, 16), 128, 0, stream>>>(Kb, Qb, Ls);
  attn_av<<<dim3(128, 16), 128, 0, stream>>>(Kb, Qb, Vtb, Ls, Zb);
  gemm_out<<<dim3(64, 8), 256, 0, stream>>>(Zb, Wob, out);
}

// Round 12
// 264.285 us; speedup vs baseline: 1.6894x; 1.6894x over previous
//
#include <hip/hip_runtime.h>
#include <hip/hip_bf16.h>

// B=8, S=1024, H=16, D=64, E=1024. I/O fp32; internal bf16 MFMA.
// attn = softmax over QUERY axis C (per key row c) of tril(K Q^T)/8.
// Two-pass: l_c = sum_{C<=c} exp(s_cC/8); then z[C] = sum_{c>=C}
// (exp(s_cC/8)/l_c) * v_c, with 1/l folded into P (vscale removed, R14).
// R20: attn_av reverted to R18/R14 single-wave form (R19's 2-wave key
// split exploded HBM traffic 37->466MB and tripled time; R10 had already
// shown attn_av is NOT wave-supply-limited). One surgical delta on top:
// av_tile_s's 12-op manual bf16 pack replaced by paired (__bf16) casts
// (pkbf -> v_cvt_pk_bf16_f32), cutting the score-path VALU chain ~45%
// (counters: VALU:MFMA = 3:1, VALU-chain-bound). RNE rounding (safer).
// attn_stats: R18 2-wave query-split form (proven +). GEMMs/cvt: R14.

#define SEQ 1024
#define DH 64
#define NH 16
#define EMB 1024
#define SCALE 0.18033688011112042f  // 0.125 * log2(e)
#define PSTR 40                     // P row stride (u16), 80B = 16B-aligned

#define ZEROM 0
#define DIAGM 1
#define FULLM 2

typedef float f32x4 __attribute__((ext_vector_type(4)));
typedef __bf16 bf16x8 __attribute__((ext_vector_type(8)));
typedef unsigned short u16x8 __attribute__((ext_vector_type(8)));

__device__ __forceinline__ unsigned short f2bf(float f) {
  union { float f; unsigned int u; } v; v.f = f;
  unsigned int u = v.u;
  return (unsigned short)((u + 0x7fffu + ((u >> 16) & 1u)) >> 16);  // RNE
}
__device__ __forceinline__ float bf2f(unsigned short u) {
  union { unsigned int u; float f; } v; v.u = ((unsigned int)u) << 16; return v.f;
}
// pack two f32 -> u32 of 2 bf16 via compiler casts (lowers to v_cvt_pk_bf16_f32)
__device__ __forceinline__ unsigned int pkbf(float a, float b) {
  union { __bf16 h[2]; unsigned int u; } v;
  v.h[0] = (__bf16)a; v.h[1] = (__bf16)b;
  return v.u;
}

__device__ __forceinline__ u16x8 ld8_f32_bf16(const float* g) {
  const float4 a = *(const float4*)g;
  const float4 b = *(const float4*)(g + 4);
  u16x8 r;
  r[0] = f2bf(a.x); r[1] = f2bf(a.y); r[2] = f2bf(a.z); r[3] = f2bf(a.w);
  r[4] = f2bf(b.x); r[5] = f2bf(b.y); r[6] = f2bf(b.z); r[7] = f2bf(b.w);
  return r;
}

__device__ __forceinline__ void gl_lds16(const void* g, void* l) {
  __builtin_amdgcn_global_load_lds(
      (const __attribute__((address_space(1))) void*)g,
      (__attribute__((address_space(3))) void*)l, 16, 0, 0);
}

// ---------------- fp32 -> bf16 conversion of X and weights ----------------
__global__ __launch_bounds__(256) void cvt_bf16(
    const float* __restrict__ X, const float* __restrict__ Wk,
    const float* __restrict__ Wq, const float* __restrict__ Wv,
    const float* __restrict__ Wo,
    unsigned short* __restrict__ Xb, unsigned short* __restrict__ Wkb,
    unsigned short* __restrict__ Wqb, unsigned short* __restrict__ Wvb,
    unsigned short* __restrict__ Wob)
{
  const size_t i = ((size_t)blockIdx.x * 256 + threadIdx.x) * 8;
  const float* src; unsigned short* dst; size_t off;
  if (i < 8388608) { src = X; dst = Xb; off = i; }
  else {
    const size_t j = i - 8388608;
    const int sel = (int)(j >> 20); off = j & 1048575;
    src = (sel == 0) ? Wk : (sel == 1) ? Wq : (sel == 2) ? Wv : Wo;
    dst = (sel == 0) ? Wkb : (sel == 1) ? Wqb : (sel == 2) ? Wvb : Wob;
  }
  *(u16x8*)(dst + off) = ld8_f32_bf16(src + off);
}

// ---------------- GEMM core (BK=64, xor-swizzled LDS) ----------------
#define GEMM_BK64_BODY(Aptr, Bptr)                                              \
  f32x4 acc[4][4] = {};                                                         \
  const int srow = lane >> 3;                                                   \
  const int scol = (((lane & 7) ^ srow)) * 8;                                   \
  const unsigned short* Ag = (Aptr) + (size_t)(mt0 + wave * 32 + srow) * EMB + scol; \
  const unsigned short* Bg = (Bptr) + (size_t)(n0 + wave * 32 + srow) * EMB + scol;  \
  char* lA = (char*)As + wave * 4096;                                           \
  char* lB = (char*)Bs + wave * 4096;                                           \
  for (int k0 = 0; k0 < EMB; k0 += 64) {                                        \
    __syncthreads();                                                            \
    _Pragma("unroll")                                                           \
    for (int ch = 0; ch < 4; ch++) {                                            \
      gl_lds16(Ag + (size_t)ch * 8 * EMB + k0, lA + ch * 1024);                 \
      gl_lds16(Bg + (size_t)ch * 8 * EMB + k0, lB + ch * 1024);                 \
    }                                                                           \
    __syncthreads();                                                            \
    _Pragma("unroll")                                                           \
    for (int half = 0; half < 2; half++) {                                      \
      bf16x8 af[4], bfr[4];                                                     \
      _Pragma("unroll")                                                         \
      for (int t = 0; t < 4; t++) {                                             \
        const int ra = wm * 64 + t * 16 + fr;                                   \
        const int rb = wn * 64 + t * 16 + fr;                                   \
        af[t]  = *(const bf16x8*)&As[ra * 64 + (((half * 4 + quad) ^ (ra & 7)) * 8)]; \
        bfr[t] = *(const bf16x8*)&Bs[rb * 64 + (((half * 4 + quad) ^ (rb & 7)) * 8)]; \
      }                                                                         \
      _Pragma("unroll")                                                         \
      for (int i = 0; i < 4; i++)                                               \
        _Pragma("unroll")                                                       \
        for (int j = 0; j < 4; j++)                                             \
          acc[i][j] = __builtin_amdgcn_mfma_f32_16x16x32_bf16(af[i], bfr[j], acc[i][j], 0, 0, 0); \
    }                                                                           \
  }

// ---------------- GEMM: QKV projection ----------------
__global__ __launch_bounds__(256) void gemm_qkv(
    const unsigned short* __restrict__ X,
    const unsigned short* __restrict__ Wk,
    const unsigned short* __restrict__ Wq,
    const unsigned short* __restrict__ Wv,
    unsigned short* __restrict__ Kb,
    unsigned short* __restrict__ Qb,
    unsigned short* __restrict__ Vt)
{
  __shared__ __align__(16) unsigned short As[128 * 64];
  __shared__ __align__(16) unsigned short Bs[128 * 64];
  const int mt0 = blockIdx.x * 128;
  const int nt = blockIdx.y;
  const int sel = nt >> 3;
  const int n0 = (nt & 7) * 128;
  const unsigned short* W = (sel == 0) ? Wk : (sel == 1) ? Wq : Wv;

  const int tid = threadIdx.x;
  const int wave = tid >> 6, lane = tid & 63;
  const int wm = wave >> 1, wn = wave & 1;
  const int fr = lane & 15, quad = lane >> 4;

  GEMM_BK64_BODY(X, W)

  const int rl = quad * 4;
  if (sel < 2) {
    unsigned short* Dst = (sel == 0) ? Kb : Qb;
#pragma unroll
    for (int i = 0; i < 4; i++) {
      const int col = n0 + wn * 64 + i * 16 + fr;
      const int a = col >> 6, h = col & 63;
#pragma unroll
      for (int j = 0; j < 4; j++) {
        const int rowb = mt0 + wm * 64 + j * 16 + rl;
#pragma unroll
        for (int r = 0; r < 4; r++) {
          const int row = rowb + r;
          const int b = row >> 10, s = row & 1023;
          Dst[(size_t)((b * NH + a) * SEQ + s) * DH + h] = f2bf(acc[j][i][r]);
        }
      }
    }
  } else {
#pragma unroll
    for (int i = 0; i < 4; i++) {
      const int col = n0 + wn * 64 + i * 16 + fr;
      const int a = col >> 6, h = col & 63;
#pragma unroll
      for (int j = 0; j < 4; j++) {
        const int rowb = mt0 + wm * 64 + j * 16 + rl;
#pragma unroll
        for (int r = 0; r < 4; r++) {
          const int row = rowb + r;
          const int b = row >> 10, s = row & 1023;
          Vt[(size_t)((b * NH + a) * DH + h) * SEQ + s] = f2bf(acc[j][i][r]);
        }
      }
    }
  }
}

// ---------------- GEMM: output projection (bf16 in, fp32 out) ----------------
__global__ __launch_bounds__(256) void gemm_out(
    const unsigned short* __restrict__ Z,
    const unsigned short* __restrict__ Wo,
    float* __restrict__ Out)
{
  __shared__ __align__(16) unsigned short As[128 * 64];
  __shared__ __align__(16) unsigned short Bs[128 * 64];
  const int mt0 = blockIdx.x * 128;
  const int n0 = blockIdx.y * 128;

  const int tid = threadIdx.x;
  const int wave = tid >> 6, lane = tid & 63;
  const int wm = wave >> 1, wn = wave & 1;
  const int fr = lane & 15, quad = lane >> 4;

  GEMM_BK64_BODY(Z, Wo)

  const int rl = quad * 4;
#pragma unroll
  for (int i = 0; i < 4; i++) {
    const int col = n0 + wn * 64 + i * 16 + fr;
#pragma unroll
    for (int j = 0; j < 4; j++) {
      const int rowb = mt0 + wm * 64 + j * 16 + rl;
#pragma unroll
      for (int r = 0; r < 4; r++)
        Out[(size_t)(rowb + r) * EMB + col] = acc[j][i][r];
    }
  }
}

// ---------------- stats tile: accumulate exp into l4 ----------------
__device__ __forceinline__ void st_tile(
    const bf16x8* ka, const bf16x8* q, float* l4, int mode, int fr, int quad)
{
  f32x4 a = {0.f, 0.f, 0.f, 0.f};
  a = __builtin_amdgcn_mfma_f32_16x16x32_bf16(ka[0], q[0], a, 0, 0, 0);
  a = __builtin_amdgcn_mfma_f32_16x16x32_bf16(ka[1], q[1], a, 0, 0, 0);
#pragma unroll
  for (int i = 0; i < 4; i++) {
    const float e = exp2f(a[i] * SCALE);
    l4[i] += (mode == FULLM || fr <= quad * 4 + i) ? e : 0.f;
  }
}

// ---------------- Pass 1: l_c = sum_{C<=c} exp(s_cC/8) ----------------
// 2-wave blocks (128 thr), query-range split (R18). grid (128, 16).
__global__ __launch_bounds__(128, 4) void attn_stats(
    const unsigned short* __restrict__ Kb, const unsigned short* __restrict__ Qb,
    float* __restrict__ Ls)
{
  __shared__ float lred[2][64];
  const int head = blockIdx.x;
  const int j = 15 - (int)blockIdx.y;
  const int cw = j * 64;
  const int tid = threadIdx.x;
  const int wave = tid >> 6;
  const int lane = tid & 63;
  const int fr = lane & 15, quad = lane >> 4;
  const unsigned short* Kl = Kb + (size_t)head * (SEQ * DH) + (size_t)fr * DH + quad * 8;
  const unsigned short* Ql = Qb + (size_t)head * (SEQ * DH) + (size_t)fr * DH + quad * 8;

  bf16x8 ka[4][2];
#pragma unroll
  for (int s = 0; s < 4; s++)
#pragma unroll
    for (int h = 0; h < 2; h++)
      ka[s][h] = *(const bf16x8*)(Kl + (size_t)(cw + s * 16) * DH + h * 32);

  float l[4][4] = {};

  // full region: 2j 32-query blocks, all FULLM. wave0 [0,j), wave1 [j,2j).
  const int qb0 = wave ? j : 0;
  const int qb1 = wave ? 2 * j : j;
  if (qb0 < qb1) {
    bf16x8 qc0[2], qc1[2];
    {
      const unsigned short* qp = Ql + (size_t)(qb0 * 32) * DH;
      qc0[0] = *(const bf16x8*)(qp);
      qc0[1] = *(const bf16x8*)(qp + 32);
      qc1[0] = *(const bf16x8*)(qp + (size_t)16 * DH);
      qc1[1] = *(const bf16x8*)(qp + (size_t)16 * DH + 32);
    }
    for (int qb = qb0; qb < qb1; qb++) {
      bf16x8 qn0[2] = {qc0[0], qc0[1]};
      bf16x8 qn1[2] = {qc1[0], qc1[1]};
      if (qb + 1 < qb1) {
        const unsigned short* qp = Ql + (size_t)((qb + 1) * 32) * DH;
        qn0[0] = *(const bf16x8*)(qp);
        qn0[1] = *(const bf16x8*)(qp + 32);
        qn1[0] = *(const bf16x8*)(qp + (size_t)16 * DH);
        qn1[1] = *(const bf16x8*)(qp + (size_t)16 * DH + 32);
      }
#pragma unroll
      for (int s = 0; s < 4; s++) {
        st_tile(ka[s], qc0, l[s], FULLM, fr, quad);
        st_tile(ka[s], qc1, l[s], FULLM, fr, quad);
      }
      qc0[0] = qn0[0]; qc0[1] = qn0[1];
      qc1[0] = qn1[0]; qc1[1] = qn1[1];
    }
  }

  if (wave == 1) {  // diagonal 64x64 block (round-0 peel, verbatim masks)
    {  // queries local [0,32)
      bf16x8 q0[2], q1[2];
#pragma unroll
      for (int h = 0; h < 2; h++) {
        q0[h] = *(const bf16x8*)(Ql + (size_t)cw * DH + h * 32);
        q1[h] = *(const bf16x8*)(Ql + (size_t)(cw + 16) * DH + h * 32);
      }
      st_tile(ka[0], q0, l[0], DIAGM, fr, quad);
      st_tile(ka[1], q0, l[1], FULLM, fr, quad);
      st_tile(ka[2], q0, l[2], FULLM, fr, quad);
      st_tile(ka[3], q0, l[3], FULLM, fr, quad);
      st_tile(ka[1], q1, l[1], DIAGM, fr, quad);
      st_tile(ka[2], q1, l[2], FULLM, fr, quad);
      st_tile(ka[3], q1, l[3], FULLM, fr, quad);
    }
    {  // queries local [32,64)
      bf16x8 q0[2], q1[2];
#pragma unroll
      for (int h = 0; h < 2; h++) {
        q0[h] = *(const bf16x8*)(Ql + (size_t)(cw + 32) * DH + h * 32);
        q1[h] = *(const bf16x8*)(Ql + (size_t)(cw + 48) * DH + h * 32);
      }
      st_tile(ka[2], q0, l[2], DIAGM, fr, quad);
      st_tile(ka[3], q0, l[3], FULLM, fr, quad);
      st_tile(ka[3], q1, l[3], DIAGM, fr, quad);
    }
  }

  // fr-shfl reduce within wave -> lred; cross-wave add; store.
#pragma unroll
  for (int s = 0; s < 4; s++)
#pragma unroll
    for (int i = 0; i < 4; i++) {
      float v = l[s][i];
      v += __shfl_xor(v, 1); v += __shfl_xor(v, 2);
      v += __shfl_xor(v, 4); v += __shfl_xor(v, 8);
      if (fr == 0) lred[wave][s * 16 + quad * 4 + i] = v;
    }
  __syncthreads();
  if (tid < 64)
    Ls[(size_t)head * SEQ + cw + tid] = lred[0][tid] + lred[1][tid];
}

// ------- load 2x float4 of l and reciprocate (keys kb..kb+31) -------
__device__ __forceinline__ void ldrl(const float* Lh, int kb, int quad,
                                     f32x4* r0, f32x4* r1)
{
  const float4 a = *(const float4*)(Lh + kb + quad * 4);
  const float4 b = *(const float4*)(Lh + kb + 16 + quad * 4);
  (*r0)[0] = __builtin_amdgcn_rcpf(a.x); (*r0)[1] = __builtin_amdgcn_rcpf(a.y);
  (*r0)[2] = __builtin_amdgcn_rcpf(a.z); (*r0)[3] = __builtin_amdgcn_rcpf(a.w);
  (*r1)[0] = __builtin_amdgcn_rcpf(b.x); (*r1)[1] = __builtin_amdgcn_rcpf(b.y);
  (*r1)[2] = __builtin_amdgcn_rcpf(b.z); (*r1)[3] = __builtin_amdgcn_rcpf(b.w);
}

// -------- av score tile -> LDS, scaled by rcp(l[key]) --------
// R20: pack via paired (__bf16) casts -> v_cvt_pk_bf16_f32 (2 insts vs 12).
__device__ __forceinline__ void av_tile_s(
    const bf16x8* ka, const bf16x8* bq, const f32x4 rl,
    unsigned short* __restrict__ pw, int mode, int fr, int quad)
{
  if (mode == ZEROM) { *(uint2*)pw = make_uint2(0u, 0u); return; }
  f32x4 acc = {0.f, 0.f, 0.f, 0.f};
  acc = __builtin_amdgcn_mfma_f32_16x16x32_bf16(ka[0], bq[0], acc, 0, 0, 0);
  acc = __builtin_amdgcn_mfma_f32_16x16x32_bf16(ka[1], bq[1], acc, 0, 0, 0);
  float p[4];
#pragma unroll
  for (int i = 0; i < 4; i++) {
    p[i] = exp2f(acc[i] * SCALE) * rl[i];   // row = key = quad*4+i
    if (mode == DIAGM && (quad * 4 + i < fr)) p[i] = 0.f;
  }
  uint2 pk;
  pk.x = pkbf(p[0], p[1]);
  pk.y = pkbf(p[2], p[3]);
  *(uint2*)pw = pk;
}

// ---------------- Pass 2: z = sum_c (P_cC / l_c) v_c ----------------
// 64 C-rows per wave, unroll-2 ping-pong, no barriers. PV-first ordering.
// grid (128 heads, 16 chunks), 64 thr. Chunk 0 heaviest, first.
__global__ __launch_bounds__(64, 2) void attn_av(
    const unsigned short* __restrict__ Kb, const unsigned short* __restrict__ Qb,
    const unsigned short* __restrict__ Vt, const float* __restrict__ Ls,
    unsigned short* __restrict__ Z)
{
  __shared__ __align__(16) unsigned short P[2][4][16 * PSTR];
  const int head = blockIdx.x;
  const int lane = threadIdx.x & 63;
  const int fr = lane & 15, quad = lane >> 4;
  const unsigned short* Kh = Kb + (size_t)head * (SEQ * DH);
  const unsigned short* Qh = Qb + (size_t)head * (SEQ * DH);
  const unsigned short* Vh = Vt + (size_t)head * (SEQ * DH);
  const float* Lh = Ls + (size_t)head * SEQ;
  const unsigned short* Kl = Kh + (size_t)fr * DH + quad * 8;
  const unsigned short* Ql = Qh + (size_t)fr * DH + quad * 8;
  const unsigned short* Vl = Vh + (size_t)fr * SEQ + quad * 8;
  const int Cw = blockIdx.y * 64;

  bf16x8 bq[4][2];
#pragma unroll
  for (int t = 0; t < 4; t++)
#pragma unroll
    for (int h = 0; h < 2; h++)
      bq[t][h] = *(const bf16x8*)(Ql + (size_t)(Cw + t * 16) * DH + h * 32);

  f32x4 zacc[4][4] = {};
  bf16x8 kA0[2], kA1[2], kB0[2], kB1[2], vA[4], vB[4];

  {  // prologue: scores(Cw) -> P[0]  (keys local [0,32))
    f32x4 rl0, rl1;
    ldrl(Lh, Cw, quad, &rl0, &rl1);
    bf16x8 kp0[2], kp1[2];
#pragma unroll
    for (int h = 0; h < 2; h++) {
      kp0[h] = *(const bf16x8*)(Kl + (size_t)Cw * DH + h * 32);
      kp1[h] = *(const bf16x8*)(Kl + (size_t)(Cw + 16) * DH + h * 32);
    }
#pragma unroll
    for (int t = 0; t < 4; t++) {
      unsigned short* pw = &P[0][t][fr * PSTR + quad * 4];
      av_tile_s(kp0, bq[t], rl0, pw, (t == 0) ? DIAGM : ZEROM, fr, quad);
      av_tile_s(kp1, bq[t], rl1, pw + 16,
                (t == 0) ? FULLM : ((t == 1) ? DIAGM : ZEROM), fr, quad);
    }
  }
  if (Cw + 32 < SEQ) {  // K for first half-A scores
#pragma unroll
    for (int h = 0; h < 2; h++) {
      kA0[h] = *(const bf16x8*)(Kl + (size_t)(Cw + 32) * DH + h * 32);
      kA1[h] = *(const bf16x8*)(Kl + (size_t)(Cw + 48) * DH + h * 32);
    }
  }
#pragma unroll
  for (int n = 0; n < 4; n++)  // V(Cw)
    vA[n] = *(const bf16x8*)(Vl + (size_t)(n * 16) * SEQ + Cw);

  for (int cb = Cw; cb < SEQ; cb += 64) {
    {  // half A: PV(cb) from P[0]; scores keys [cb+32,cb+64) -> P[1]
      const int nxt = cb + 32;
      bf16x8 pf[4];
#pragma unroll
      for (int t = 0; t < 4; t++)
        pf[t] = *(const bf16x8*)&P[0][t][fr * PSTR + quad * 8];
      f32x4 rl0, rl1;
      if (nxt < SEQ) {
        ldrl(Lh, nxt, quad, &rl0, &rl1);
        if (cb + 64 < SEQ) {
#pragma unroll
          for (int h = 0; h < 2; h++) {
            kB0[h] = *(const bf16x8*)(Kl + (size_t)(cb + 64) * DH + h * 32);
            kB1[h] = *(const bf16x8*)(Kl + (size_t)(cb + 80) * DH + h * 32);
          }
        }
#pragma unroll
        for (int n = 0; n < 4; n++)
          vB[n] = *(const bf16x8*)(Vl + (size_t)(n * 16) * SEQ + nxt);
      }
#pragma unroll
      for (int t = 0; t < 4; t++)
#pragma unroll
        for (int n = 0; n < 4; n++)
          zacc[t][n] = __builtin_amdgcn_mfma_f32_16x16x32_bf16(pf[t], vA[n], zacc[t][n], 0, 0, 0);
      if (nxt < SEQ) {
        const bool sp = (nxt == Cw + 32);  // keys local [32,64)
#pragma unroll
        for (int t = 0; t < 4; t++) {
          unsigned short* pw = &P[1][t][fr * PSTR + quad * 4];
          av_tile_s(kA0, bq[t], rl0, pw,
                    sp ? ((t < 2) ? FULLM : ((t == 2) ? DIAGM : ZEROM)) : FULLM, fr, quad);
          av_tile_s(kA1, bq[t], rl1, pw + 16,
                    sp ? ((t < 3) ? FULLM : DIAGM) : FULLM, fr, quad);
        }
      }
    }
    {  // half B: PV(cb+32) from P[1]; scores keys [cb+64,cb+96) -> P[0]
      const int cb2 = cb + 32;  // always < SEQ (even trip count)
      const int nxt = cb2 + 32;
      bf16x8 pf[4];
#pragma unroll
      for (int t = 0; t < 4; t++)
        pf[t] = *(const bf16x8*)&P[1][t][fr * PSTR + quad * 8];
      f32x4 rl0, rl1;
      if (nxt < SEQ) {
        ldrl(Lh, nxt, quad, &rl0, &rl1);
        if (cb2 + 64 < SEQ) {
#pragma unroll
          for (int h = 0; h < 2; h++) {
            kA0[h] = *(const bf16x8*)(Kl + (size_t)(cb2 + 64) * DH + h * 32);
            kA1[h] = *(const bf16x8*)(Kl + (size_t)(cb2 + 80) * DH + h * 32);
          }
        }
#pragma unroll
        for (int n = 0; n < 4; n++)
          vA[n] = *(const bf16x8*)(Vl + (size_t)(n * 16) * SEQ + nxt);
      }
#pragma unroll
      for (int t = 0; t < 4; t++)
#pragma unroll
        for (int n = 0; n < 4; n++)
          zacc[t][n] = __builtin_amdgcn_mfma_f32_16x16x32_bf16(pf[t], vB[n], zacc[t][n], 0, 0, 0);
      if (nxt < SEQ) {
#pragma unroll
        for (int t = 0; t < 4; t++) {
          unsigned short* pw = &P[0][t][fr * PSTR + quad * 4];
          av_tile_s(kB0, bq[t], rl0, pw, FULLM, fr, quad);
          av_tile_s(kB1, bq[t], rl1, pw + 16, FULLM, fr, quad);
        }
      }
    }
  }

  const int b = head >> 4, a = head & 15;
#pragma unroll
  for (int t = 0; t < 4; t++)
#pragma unroll
    for (int n = 0; n < 4; n++)
#pragma unroll
      for (int i = 0; i < 4; i++) {
        const int C = Cw + t * 16 + quad * 4 + i;
        const int f = a * DH + n * 16 + fr;
        Z[((size_t)(b * SEQ + C) << 10) + f] = f2bf(zacc[t][n][i]);
      }
}

// ---------------- launch ----------------
extern "C" void kernel_launch(void* const* d_in, const int* in_sizes, int n_in,
                              void* d_out, int out_size, void* d_ws, size_t ws_size,
                              hipStream_t stream)
{
  const float* x  = (const float*)d_in[0];
  const float* wk = (const float*)d_in[1];
  const float* wq = (const float*)d_in[2];
  const float* wv = (const float*)d_in[3];
  const float* wo = (const float*)d_in[4];
  float* out = (float*)d_out;
  char* ws = (char*)d_ws;

  unsigned short* Xb  = (unsigned short*)(ws);            // 16 MB (aliased by Zb)
  unsigned short* Zb  = (unsigned short*)(ws);
  unsigned short* Kb  = (unsigned short*)(ws + 16777216);
  unsigned short* Qb  = (unsigned short*)(ws + 33554432);
  unsigned short* Vtb = (unsigned short*)(ws + 50331648);
  unsigned short* Wkb = (unsigned short*)(ws + 67108864);
  unsigned short* Wqb = (unsigned short*)(ws + 69206016);
  unsigned short* Wvb = (unsigned short*)(ws + 71303168);
  unsigned short* Wob = (unsigned short*)(ws + 73400320);
  float* Ls = (float*)(ws + 75497472);

  cvt_bf16<<<dim3(6144), 256, 0, stream>>>(x, wk, wq, wv, wo, Xb, Wkb, Wqb, Wvb, Wob);
  gemm_qkv<<<dim3(64, 24), 256, 0, stream>>>(Xb, Wkb, Wqb, Wvb, Kb, Qb, Vtb);
  attn_stats<<<dim3(128, 16), 128, 0, stream>>>(Kb, Qb, Ls);
  attn_av<<<dim3(128, 16), 64, 0, stream>>>(Kb, Qb, Vtb, Ls, Zb);
  gemm_out<<<dim3(64, 8), 256, 0, stream>>>(Zb, Wob, out);
}